// Round 2
// baseline (2527.573 us; speedup 1.0000x reference)
//
#include <hip/hip_runtime.h>
#include <hip/hip_bf16.h>
#include <cstdint>

typedef __attribute__((ext_vector_type(8))) short short8;
typedef __attribute__((ext_vector_type(4))) float f32x4;
typedef __attribute__((ext_vector_type(4))) short short4v;

__device__ __forceinline__ float b2f(short s) {
    unsigned u = ((unsigned)(unsigned short)s) << 16;
    return __builtin_bit_cast(float, u);
}
__device__ __forceinline__ short f2b(float f) {
    unsigned u = __builtin_bit_cast(unsigned, f);
    u += 0x7fff + ((u >> 16) & 1);   // RNE
    return (short)(u >> 16);
}

__device__ __forceinline__ void async16(const void* g, void* l) {
    __builtin_amdgcn_global_load_lds(
        (const __attribute__((address_space(1))) unsigned int*)g,
        (__attribute__((address_space(3))) unsigned int*)l, 16, 0, 0);
}

// ---------------- GEMM: C[M,512] = A[M,512] @ Bt[512,512]^T + bias, opt. GELU ----------------
#define BM 128
#define BN 128
#define BKK 64

template<bool GELU>
__global__ __launch_bounds__(256)
void gemm_bt(const short* __restrict__ A, const short* __restrict__ Bt,
             const float* __restrict__ bias, short* __restrict__ C) {
    __shared__ alignas(16) short As[BM * BKK];
    __shared__ alignas(16) short Bs[BN * BKK];
    const int tid  = threadIdx.x;
    const int lane = tid & 63;
    const int w    = tid >> 6;
    const int wr   = w >> 1, wc = w & 1;
    const long arow0 = (long)blockIdx.x * BM;
    const long brow0 = (long)blockIdx.y * BN;
    const int  K = 512;

    f32x4 acc[4][4] = {};

    const int srow = lane >> 3;        // 0..7
    const int scol = (lane & 7) * 8;   // element col (16B granules)

    for (int k0 = 0; k0 < K; k0 += BKK) {
        __syncthreads();
#pragma unroll
        for (int i = 0; i < 4; ++i) {
            const int r0 = (i * 4 + w) * 8;   // wave-uniform row group
            async16(A  + (arow0 + r0 + srow) * K + k0 + scol, &As[r0 * BKK]);
            async16(Bt + (brow0 + r0 + srow) * K + k0 + scol, &Bs[r0 * BKK]);
        }
        __syncthreads();
        const int lr = lane & 15;
#pragma unroll
        for (int kk = 0; kk < BKK; kk += 32) {
            const int ko = kk + (lane >> 4) * 8;
            short8 a[4], b[4];
#pragma unroll
            for (int m = 0; m < 4; ++m)
                a[m] = *(const short8*)&As[(wr * 64 + m * 16 + lr) * BKK + ko];
#pragma unroll
            for (int n = 0; n < 4; ++n)
                b[n] = *(const short8*)&Bs[(wc * 64 + n * 16 + lr) * BKK + ko];
#pragma unroll
            for (int m = 0; m < 4; ++m)
#pragma unroll
                for (int n = 0; n < 4; ++n)
                    acc[m][n] = __builtin_amdgcn_mfma_f32_16x16x32_bf16(
                        a[m], b[n], acc[m][n], 0, 0, 0);
        }
    }

    const int cl = lane & 15;
    const int rl = (lane >> 4) * 4;
#pragma unroll
    for (int n = 0; n < 4; ++n) {
        const int col = (int)brow0 + wc * 64 + n * 16 + cl;
        const float bs = bias[col];
#pragma unroll
        for (int m = 0; m < 4; ++m) {
#pragma unroll
            for (int i = 0; i < 4; ++i) {
                const long row = arow0 + wr * 64 + m * 16 + rl + i;
                float c = acc[m][n][i] + bs;
                if (GELU) c = 0.5f * c * (1.0f + erff(c * 0.70710678118654752f));
                C[row * 512 + col] = f2b(c);
            }
        }
    }
}

// ---------------- transpose+convert: dst[n][k] = bf16(src[k][n]), 512x512 per z ----------------
__global__ __launch_bounds__(256)
void transpose_conv(const float* __restrict__ src, short* __restrict__ dst) {
    __shared__ float t[32][33];
    const long moff = (long)blockIdx.z * 512 * 512;
    const float* s = src + moff;
    short* d = dst + moff;
    const int tx = threadIdx.x & 31, ty = threadIdx.x >> 5;  // ty 0..7
    const int bi = blockIdx.x, bj = blockIdx.y;
#pragma unroll
    for (int j = 0; j < 4; ++j)
        t[ty + j * 8][tx] = s[(long)(bi * 32 + ty + j * 8) * 512 + bj * 32 + tx];
    __syncthreads();
#pragma unroll
    for (int j = 0; j < 4; ++j)
        d[(long)(bj * 32 + ty + j * 8) * 512 + bi * 32 + tx] = f2b(t[tx][ty + j * 8]);
}

// ---------------- f32 -> bf16 elementwise ----------------
__global__ __launch_bounds__(256)
void conv_f32_bf16(const float* __restrict__ src, short* __restrict__ dst, long n) {
    long i = ((long)blockIdx.x * 256 + threadIdx.x) * 4;
    if (i >= n) return;
    float4 f = *(const float4*)&src[i];
    short4v o;
    o[0] = f2b(f.x); o[1] = f2b(f.y); o[2] = f2b(f.z); o[3] = f2b(f.w);
    *(short4v*)&dst[i] = o;
}

// ---------------- LayerNorm + L2 normalize: one wave per 512-row ----------------
__global__ __launch_bounds__(256)
void ln_normalize(const short* __restrict__ in, const float* __restrict__ g,
                  const float* __restrict__ bta, short* __restrict__ outz, int nrows) {
    const int wid = threadIdx.x >> 6, lane = threadIdx.x & 63;
    const long row = (long)blockIdx.x * 4 + wid;
    if (row >= nrows) return;
    short8 t = *(const short8*)&in[row * 512 + lane * 8];
    float v[8];
    float s = 0.f, ss = 0.f;
#pragma unroll
    for (int j = 0; j < 8; ++j) { v[j] = b2f(t[j]); s += v[j]; ss += v[j] * v[j]; }
#pragma unroll
    for (int o = 1; o < 64; o <<= 1) { s += __shfl_xor(s, o, 64); ss += __shfl_xor(ss, o, 64); }
    const float mu = s * (1.f / 512.f);
    const float var = ss * (1.f / 512.f) - mu * mu;
    const float rs = rsqrtf(var + 1e-5f);
    float y[8]; float nsq = 0.f;
#pragma unroll
    for (int j = 0; j < 8; ++j) {
        const int col = lane * 8 + j;
        y[j] = (v[j] - mu) * rs * g[col] + bta[col];
        nsq += y[j] * y[j];
    }
#pragma unroll
    for (int o = 1; o < 64; o <<= 1) nsq += __shfl_xor(nsq, o, 64);
    const float inv = 1.f / fmaxf(sqrtf(nsq), 1e-8f);
    short8 o8;
#pragma unroll
    for (int j = 0; j < 8; ++j) o8[j] = f2b(y[j] * inv);
    *(short8*)&outz[row * 512 + lane * 8] = o8;
}

// ---------------- loss: per-b 12x12 Gram + per-k logsumexp ----------------
// Z slots laid out with stride CH*512 (CH rows in this chunk)
__global__ __launch_bounds__(64)
void loss_kernel(const short* __restrict__ Z, float* __restrict__ out, int CH) {
    const int b = blockIdx.x;
    const int lane = threadIdx.x;
    float v[12][8];
#pragma unroll
    for (int sIdx = 0; sIdx < 12; ++sIdx) {
        short8 t = *(const short8*)&Z[((long)sIdx * CH + b) * 512 + lane * 8];
#pragma unroll
        for (int j = 0; j < 8; ++j) v[sIdx][j] = b2f(t[j]);
    }
    __shared__ float G[12][12];
#pragma unroll
    for (int i = 0; i < 12; ++i) {
#pragma unroll
        for (int j = i + 1; j < 12; ++j) {
            float p = 0.f;
#pragma unroll
            for (int t = 0; t < 8; ++t) p += v[i][t] * v[j][t];
#pragma unroll
            for (int o = 1; o < 64; o <<= 1) p += __shfl_xor(p, o, 64);
            if (lane == 0) { G[i][j] = p; G[j][i] = p; }
        }
    }
    __syncthreads();
    float contrib = 0.f;
    if (lane >= 1 && lane <= 11) {
        const int k = lane;
        const float pos = G[0][k];
        float mx = pos;
        for (int l = 1; l <= 11; ++l) if (l != k) mx = fmaxf(mx, G[l][k]);
        float sum = expf(pos - mx);
        for (int l = 1; l <= 11; ++l) if (l != k) sum += expf(G[l][k] - mx);
        contrib = pos - (mx + logf(sum));
    }
#pragma unroll
    for (int o = 1; o < 64; o <<= 1) contrib += __shfl_xor(contrib, o, 64);
    if (lane == 0) out[b] = -contrib;
}

// ---------------- host ----------------
extern "C" void kernel_launch(void* const* d_in, const int* in_sizes, int n_in,
                              void* d_out, int out_size, void* d_ws, size_t ws_size,
                              hipStream_t stream) {
    const float* x    = (const float*)d_in[0];
    const float* tW1  = (const float*)d_in[1];
    const float* tb1  = (const float*)d_in[2];
    const float* tW2  = (const float*)d_in[3];
    const float* tb2  = (const float*)d_in[4];
    const float* tW3  = (const float*)d_in[5];
    const float* tb3  = (const float*)d_in[6];
    const float* eW1  = (const float*)d_in[7];
    const float* eb1  = (const float*)d_in[8];
    const float* eW2  = (const float*)d_in[9];
    const float* eb2  = (const float*)d_in[10];
    const float* eW3  = (const float*)d_in[11];
    const float* eb3  = (const float*)d_in[12];
    const float* ln_g = (const float*)d_in[13];
    const float* ln_b = (const float*)d_in[14];

    const int  B    = in_sizes[0] / 512;   // 16384
    const int  K    = 11;
    const long WMAT = 512L * 512L;

    // ---- adaptive chunking so we never exceed ws_size ----
    // footprint = weights (36*WMAT bf16) + 15 chunk-slabs (xbc, hA, hB, 12x z) bf16
    int  c  = 1;
    long CH = B;
    for (;;) {
        CH = (long)B / c;
        size_t need = (size_t)36 * WMAT * 2 + (size_t)15 * CH * 512 * 2 + 4096;
        if (need <= ws_size || CH <= 128) break;
        c <<= 1;
    }

    short* wt  = (short*)d_ws;             // 36 transposed bf16 weight mats
    short* xbc = wt  + 36L * WMAT;         // chunk of x in bf16
    short* hA  = xbc + CH * 512;
    short* hB  = hA  + CH * 512;
    short* zst = hB  + CH * 512;           // 12 slabs of CH*512 bf16

    // --- weight transpose+convert (once) ---
    {
        dim3 tgK(16, 16, 11), tg1(16, 16, 1);
        transpose_conv<<<tgK, 256, 0, stream>>>(tW1, wt + 0L * WMAT);
        transpose_conv<<<tgK, 256, 0, stream>>>(tW2, wt + 11L * WMAT);
        transpose_conv<<<tgK, 256, 0, stream>>>(tW3, wt + 22L * WMAT);
        transpose_conv<<<tg1, 256, 0, stream>>>(eW1, wt + 33L * WMAT);
        transpose_conv<<<tg1, 256, 0, stream>>>(eW2, wt + 34L * WMAT);
        transpose_conv<<<tg1, 256, 0, stream>>>(eW3, wt + 35L * WMAT);
    }

    const dim3 gg((unsigned)(CH / BM), 512 / BN);
    const dim3 lng((unsigned)((CH + 3) / 4));
    const long SC = CH * 512;

    for (int ch = 0; ch < c; ++ch) {
        conv_f32_bf16<<<(unsigned)((SC / 4 + 255) / 256), 256, 0, stream>>>(
            x + (long)ch * SC, xbc, SC);

        // encoder on x -> z slot 0
        gemm_bt<true ><<<gg, 256, 0, stream>>>(xbc, wt + 33L * WMAT, eb1, hA);
        gemm_bt<true ><<<gg, 256, 0, stream>>>(hA,  wt + 34L * WMAT, eb2, hB);
        gemm_bt<false><<<gg, 256, 0, stream>>>(hB,  wt + 35L * WMAT, eb3, hA);
        ln_normalize<<<lng, 256, 0, stream>>>(hA, ln_g, ln_b, zst, (int)CH);

        for (int k = 0; k < K; ++k) {
            gemm_bt<true ><<<gg, 256, 0, stream>>>(xbc, wt + (long)k * WMAT,        tb1 + (long)k * 512, hA);
            gemm_bt<true ><<<gg, 256, 0, stream>>>(hA,  wt + (long)(11 + k) * WMAT, tb2 + (long)k * 512, hB);
            gemm_bt<false><<<gg, 256, 0, stream>>>(hB,  wt + (long)(22 + k) * WMAT, tb3 + (long)k * 512, hA);
            gemm_bt<true ><<<gg, 256, 0, stream>>>(hA,  wt + 33L * WMAT, eb1, hB);
            gemm_bt<true ><<<gg, 256, 0, stream>>>(hB,  wt + 34L * WMAT, eb2, hA);
            gemm_bt<false><<<gg, 256, 0, stream>>>(hA,  wt + 35L * WMAT, eb3, hB);
            ln_normalize<<<lng, 256, 0, stream>>>(hB, ln_g, ln_b, zst + (long)(k + 1) * SC, (int)CH);
        }

        loss_kernel<<<(unsigned)CH, 64, 0, stream>>>(zst, (float*)d_out + (long)ch * CH, (int)CH);
    }
}

// Round 3
// 1470.062 us; speedup vs baseline: 1.7194x; 1.7194x over previous
//
#include <hip/hip_runtime.h>
#include <hip/hip_bf16.h>
#include <cstdint>

typedef __attribute__((ext_vector_type(8))) short short8;
typedef __attribute__((ext_vector_type(4))) float f32x4;
typedef __attribute__((ext_vector_type(4))) short short4v;

__device__ __forceinline__ float b2f(short s) {
    unsigned u = ((unsigned)(unsigned short)s) << 16;
    return __builtin_bit_cast(float, u);
}
__device__ __forceinline__ short f2b(float f) {
    unsigned u = __builtin_bit_cast(unsigned, f);
    u += 0x7fff + ((u >> 16) & 1);   // RNE
    return (short)(u >> 16);
}

__device__ __forceinline__ void async16(const void* g, void* l) {
    __builtin_amdgcn_global_load_lds(
        (const __attribute__((address_space(1))) unsigned int*)g,
        (__attribute__((address_space(3))) unsigned int*)l, 16, 0, 0);
}

// ---- GEMM: C[M,512] = A[M,512] @ Bt[512,512]^T + bias, opt GELU; batched over blockIdx.z ----
#define BM 128
#define BN 128
#define BKK 64

template<bool GELU>
__global__ __launch_bounds__(256)
void gemm_bt(const short* __restrict__ A, long sA,
             const short* __restrict__ Bt, long sB,
             const float* __restrict__ bias, long sBias,
             short* __restrict__ C, long sC) {
    const int z = blockIdx.z;
    A    += (long)z * sA;
    Bt   += (long)z * sB;
    bias += (long)z * sBias;
    C    += (long)z * sC;

    __shared__ alignas(16) short As[BM * BKK];
    __shared__ alignas(16) short Bs[BN * BKK];
    const int tid  = threadIdx.x;
    const int lane = tid & 63;
    const int w    = tid >> 6;
    const int wr   = w >> 1, wc = w & 1;
    const long arow0 = (long)blockIdx.x * BM;
    const long brow0 = (long)blockIdx.y * BN;
    const int  K = 512;

    f32x4 acc[4][4] = {};

    const int srow = lane >> 3;        // 0..7
    const int scol = (lane & 7) * 8;   // element col (16B granules)

    for (int k0 = 0; k0 < K; k0 += BKK) {
        __syncthreads();
#pragma unroll
        for (int i = 0; i < 4; ++i) {
            const int r0 = (i * 4 + w) * 8;   // wave-uniform row group
            async16(A  + (arow0 + r0 + srow) * K + k0 + scol, &As[r0 * BKK]);
            async16(Bt + (brow0 + r0 + srow) * K + k0 + scol, &Bs[r0 * BKK]);
        }
        __syncthreads();
        const int lr = lane & 15;
#pragma unroll
        for (int kk = 0; kk < BKK; kk += 32) {
            const int ko = kk + (lane >> 4) * 8;
            short8 a[4], b[4];
#pragma unroll
            for (int m = 0; m < 4; ++m)
                a[m] = *(const short8*)&As[(wr * 64 + m * 16 + lr) * BKK + ko];
#pragma unroll
            for (int n = 0; n < 4; ++n)
                b[n] = *(const short8*)&Bs[(wc * 64 + n * 16 + lr) * BKK + ko];
#pragma unroll
            for (int m = 0; m < 4; ++m)
#pragma unroll
                for (int n = 0; n < 4; ++n)
                    acc[m][n] = __builtin_amdgcn_mfma_f32_16x16x32_bf16(
                        a[m], b[n], acc[m][n], 0, 0, 0);
        }
    }

    const int cl = lane & 15;
    const int rl = (lane >> 4) * 4;
#pragma unroll
    for (int n = 0; n < 4; ++n) {
        const int col = (int)brow0 + wc * 64 + n * 16 + cl;
        const float bs = bias[col];
#pragma unroll
        for (int m = 0; m < 4; ++m) {
#pragma unroll
            for (int i = 0; i < 4; ++i) {
                const long row = arow0 + wr * 64 + m * 16 + rl + i;
                float cv = acc[m][n][i] + bs;
                if (GELU) cv = 0.5f * cv * (1.0f + erff(cv * 0.70710678118654752f));
                C[row * 512 + col] = f2b(cv);
            }
        }
    }
}

// ---- transpose+convert: dst[n][k] = bf16(src[k][n]), one 512x512 matrix per blockIdx.z ----
__global__ __launch_bounds__(256)
void transpose_conv(const float* __restrict__ src, short* __restrict__ dst) {
    __shared__ float t[32][33];
    const long moff = (long)blockIdx.z * 512 * 512;
    const float* s = src + moff;
    short* d = dst + moff;
    const int tx = threadIdx.x & 31, ty = threadIdx.x >> 5;  // ty 0..7
    const int bi = blockIdx.x, bj = blockIdx.y;
#pragma unroll
    for (int j = 0; j < 4; ++j)
        t[ty + j * 8][tx] = s[(long)(bi * 32 + ty + j * 8) * 512 + bj * 32 + tx];
    __syncthreads();
#pragma unroll
    for (int j = 0; j < 4; ++j)
        d[(long)(bj * 32 + ty + j * 8) * 512 + bi * 32 + tx] = f2b(t[tx][ty + j * 8]);
}

// ---- f32 -> bf16 elementwise ----
__global__ __launch_bounds__(256)
void conv_f32_bf16(const float* __restrict__ src, short* __restrict__ dst, long n) {
    long i = ((long)blockIdx.x * 256 + threadIdx.x) * 4;
    if (i >= n) return;
    float4 f = *(const float4*)&src[i];
    short4v o;
    o[0] = f2b(f.x); o[1] = f2b(f.y); o[2] = f2b(f.z); o[3] = f2b(f.w);
    *(short4v*)&dst[i] = o;
}

// ---- LayerNorm + L2 normalize: one wave per 512-row ----
__global__ __launch_bounds__(256)
void ln_normalize(const short* __restrict__ in, const float* __restrict__ g,
                  const float* __restrict__ bta, short* __restrict__ outz, long nrows) {
    const int wid = threadIdx.x >> 6, lane = threadIdx.x & 63;
    const long row = (long)blockIdx.x * 4 + wid;
    if (row >= nrows) return;
    short8 t = *(const short8*)&in[row * 512 + lane * 8];
    float v[8];
    float s = 0.f, ss = 0.f;
#pragma unroll
    for (int j = 0; j < 8; ++j) { v[j] = b2f(t[j]); s += v[j]; ss += v[j] * v[j]; }
#pragma unroll
    for (int o = 1; o < 64; o <<= 1) { s += __shfl_xor(s, o, 64); ss += __shfl_xor(ss, o, 64); }
    const float mu = s * (1.f / 512.f);
    const float var = ss * (1.f / 512.f) - mu * mu;
    const float rs = rsqrtf(var + 1e-5f);
    float y[8]; float nsq = 0.f;
#pragma unroll
    for (int j = 0; j < 8; ++j) {
        const int col = lane * 8 + j;
        y[j] = (v[j] - mu) * rs * g[col] + bta[col];
        nsq += y[j] * y[j];
    }
#pragma unroll
    for (int o = 1; o < 64; o <<= 1) nsq += __shfl_xor(nsq, o, 64);
    const float inv = 1.f / fmaxf(sqrtf(nsq), 1e-8f);
    short8 o8;
#pragma unroll
    for (int j = 0; j < 8; ++j) o8[j] = f2b(y[j] * inv);
    *(short8*)&outz[row * 512 + lane * 8] = o8;
}

// ---- loss: 4 waves/block, one b per wave; 12x12 Gram + per-k logsumexp ----
__global__ __launch_bounds__(256)
void loss_kernel(const short* __restrict__ Z, float* __restrict__ out, int CH) {
    const int wid = threadIdx.x >> 6, lane = threadIdx.x & 63;
    const long b = (long)blockIdx.x * 4 + wid;
    __shared__ float G[4][12][12];
    float v[12][8];
#pragma unroll
    for (int sIdx = 0; sIdx < 12; ++sIdx) {
        short8 t = *(const short8*)&Z[((long)sIdx * CH + b) * 512 + lane * 8];
#pragma unroll
        for (int j = 0; j < 8; ++j) v[sIdx][j] = b2f(t[j]);
    }
#pragma unroll
    for (int i = 0; i < 12; ++i) {
#pragma unroll
        for (int j = i + 1; j < 12; ++j) {
            float p = 0.f;
#pragma unroll
            for (int t = 0; t < 8; ++t) p += v[i][t] * v[j][t];
#pragma unroll
            for (int o = 1; o < 64; o <<= 1) p += __shfl_xor(p, o, 64);
            if (lane == 0) { G[wid][i][j] = p; G[wid][j][i] = p; }
        }
    }
    __syncthreads();
    float contrib = 0.f;
    if (lane >= 1 && lane <= 11) {
        const int k = lane;
        const float pos = G[wid][0][k];
        float mx = pos;
        for (int l = 1; l <= 11; ++l) if (l != k) mx = fmaxf(mx, G[wid][l][k]);
        float sum = expf(pos - mx);
        for (int l = 1; l <= 11; ++l) if (l != k) sum += expf(G[wid][l][k] - mx);
        contrib = pos - (mx + logf(sum));
    }
#pragma unroll
    for (int o = 1; o < 64; o <<= 1) contrib += __shfl_xor(contrib, o, 64);
    if (lane == 0) out[b] = -contrib;
}

// ---------------- host ----------------
extern "C" void kernel_launch(void* const* d_in, const int* in_sizes, int n_in,
                              void* d_out, int out_size, void* d_ws, size_t ws_size,
                              hipStream_t stream) {
    const float* x    = (const float*)d_in[0];
    const float* tW1  = (const float*)d_in[1];
    const float* tb1  = (const float*)d_in[2];
    const float* tW2  = (const float*)d_in[3];
    const float* tb2  = (const float*)d_in[4];
    const float* tW3  = (const float*)d_in[5];
    const float* tb3  = (const float*)d_in[6];
    const float* eW1  = (const float*)d_in[7];
    const float* eb1  = (const float*)d_in[8];
    const float* eW2  = (const float*)d_in[9];
    const float* eb2  = (const float*)d_in[10];
    const float* eW3  = (const float*)d_in[11];
    const float* eb3  = (const float*)d_in[12];
    const float* ln_g = (const float*)d_in[13];
    const float* ln_b = (const float*)d_in[14];

    const int  B    = in_sizes[0] / 512;   // 16384
    const long WMAT = 512L * 512L;

    // ---- adaptive chunking: footprint = weights + 3 slabs of 12*CH*512 bf16 ----
    int  c  = 1;
    long CH = B;
    for (;;) {
        CH = (long)B / c;
        size_t need = (size_t)36 * WMAT * 2 + (size_t)36 * CH * 512 * 2 + 4096;
        if (need <= ws_size || CH <= 256) break;
        c <<= 1;
    }
    const long SLAB = 12L * CH * 512;      // elements per 12-view slab

    short* wt  = (short*)d_ws;             // 36 transposed bf16 weight mats
    short* X12 = wt  + 36L * WMAT;         // [12, CH, 512]: slot0 = x, slots 1..11 = t_k(x); reused as z-store
    short* hA  = X12 + SLAB;               // [12, CH, 512] scratch
    short* hB  = hA  + SLAB;               // [12, CH, 512] scratch

    // --- weight transpose+convert (once) ---
    {
        dim3 tgK(16, 16, 11), tg1(16, 16, 1);
        transpose_conv<<<tgK, 256, 0, stream>>>(tW1, wt + 0L * WMAT);
        transpose_conv<<<tgK, 256, 0, stream>>>(tW2, wt + 11L * WMAT);
        transpose_conv<<<tgK, 256, 0, stream>>>(tW3, wt + 22L * WMAT);
        transpose_conv<<<tg1, 256, 0, stream>>>(eW1, wt + 33L * WMAT);
        transpose_conv<<<tg1, 256, 0, stream>>>(eW2, wt + 34L * WMAT);
        transpose_conv<<<tg1, 256, 0, stream>>>(eW3, wt + 35L * WMAT);
    }

    const long SC = CH * 512;              // one [CH,512] slab
    const dim3 gT((unsigned)(CH / BM), 512 / BN, 11);        // batched transforms
    const dim3 gE((unsigned)(12 * CH / BM), 512 / BN, 1);    // encoder over all 12 views
    const dim3 lng((unsigned)((12 * CH) / 4));

    for (int ch = 0; ch < c; ++ch) {
        // x chunk -> bf16 into X12 slot 0
        conv_f32_bf16<<<(unsigned)((SC / 4 + 255) / 256), 256, 0, stream>>>(
            x + (long)ch * SC, X12, SC);

        // 11 learned transforms, batched over z
        gemm_bt<true ><<<gT, 256, 0, stream>>>(X12, 0,  wt + 0L * WMAT,  WMAT, tb1, 512, hA, SC);
        gemm_bt<true ><<<gT, 256, 0, stream>>>(hA,  SC, wt + 11L * WMAT, WMAT, tb2, 512, hB, SC);
        gemm_bt<false><<<gT, 256, 0, stream>>>(hB,  SC, wt + 22L * WMAT, WMAT, tb3, 512, X12 + SC, SC);

        // shared encoder over all 12 views at once (M = 12*CH)
        gemm_bt<true ><<<gE, 256, 0, stream>>>(X12, 0, wt + 33L * WMAT, 0, eb1, 0, hA, 0);
        gemm_bt<true ><<<gE, 256, 0, stream>>>(hA,  0, wt + 34L * WMAT, 0, eb2, 0, hB, 0);
        gemm_bt<false><<<gE, 256, 0, stream>>>(hB,  0, wt + 35L * WMAT, 0, eb3, 0, hA, 0);

        // LN + L2-normalize all 12*CH rows; write z back into X12 (free after E1 read)
        ln_normalize<<<lng, 256, 0, stream>>>(hA, ln_g, ln_b, X12, 12L * CH);

        // per-sample 12x12 Gram + logsumexp loss
        loss_kernel<<<(unsigned)(CH / 4), 256, 0, stream>>>(X12, (float*)d_out + (long)ch * CH, (int)CH);
    }
}

// Round 4
// 1368.163 us; speedup vs baseline: 1.8474x; 1.0745x over previous
//
#include <hip/hip_runtime.h>
#include <hip/hip_bf16.h>
#include <cstdint>

typedef __attribute__((ext_vector_type(8))) short short8;
typedef __attribute__((ext_vector_type(4))) float f32x4;
typedef __attribute__((ext_vector_type(4))) short short4v;

__device__ __forceinline__ float b2f(short s) {
    unsigned u = ((unsigned)(unsigned short)s) << 16;
    return __builtin_bit_cast(float, u);
}
__device__ __forceinline__ short f2b(float f) {
    unsigned u = __builtin_bit_cast(unsigned, f);
    u += 0x7fff + ((u >> 16) & 1);   // RNE
    return (short)(u >> 16);
}

__device__ __forceinline__ float gelu_t(float x) {
    // tanh-form GELU; |err vs erf-form| < ~3e-3 absolute (<< bf16 rounding here)
    float u = 0.7978845608028654f * (x + 0.044715f * x * x * x);
    float e = __expf(2.0f * u);
    float t = 1.0f - __fdividef(2.0f, e + 1.0f);
    return 0.5f * x * (1.0f + t);
}

__device__ __forceinline__ void async16(const void* g, void* l) {
    __builtin_amdgcn_global_load_lds(
        (const __attribute__((address_space(1))) unsigned int*)g,
        (__attribute__((address_space(3))) unsigned int*)l, 16, 0, 0);
}

// ---- GEMM: C[M,512] = A[M,512] @ Bt[512,512]^T + bias, opt GELU; batched over blockIdx.z ----
#define BM 128
#define BN 128
#define BKK 64

template<bool GELU>
__global__ __launch_bounds__(256)
void gemm_bt(const short* __restrict__ A, long sA,
             const short* __restrict__ Bt, long sB,
             const float* __restrict__ bias, long sBias,
             short* __restrict__ C, long sC) {
    const int z = blockIdx.z;
    A    += (long)z * sA;
    Bt   += (long)z * sB;
    bias += (long)z * sBias;
    C    += (long)z * sC;

    // K-loop: As = smem[0:8192), Bs = smem[8192:16384)
    // epilogue: per-wave [64][72] tiles, 4 * 4608 shorts = 36864 B total
    __shared__ alignas(16) short smem[4 * 64 * 72];
    short* As = smem;
    short* Bs = smem + BM * BKK;

    const int tid  = threadIdx.x;
    const int lane = tid & 63;
    const int w    = tid >> 6;
    const int wr   = w >> 1, wc = w & 1;
    const long arow0 = (long)blockIdx.x * BM;
    const long brow0 = (long)blockIdx.y * BN;
    const int  K = 512;

    f32x4 acc[4][4] = {};

    const int srow = lane >> 3;                    // 0..7 (row&7 of staged row)
    const int scol = ((lane & 7) ^ srow) * 8;      // pre-swizzled global chunk (T2 both-sides)

    for (int k0 = 0; k0 < K; k0 += BKK) {
        __syncthreads();
#pragma unroll
        for (int i = 0; i < 4; ++i) {
            const int r0 = (i * 4 + w) * 8;        // wave-uniform row group
            async16(A  + (arow0 + r0 + srow) * K + k0 + scol, &As[r0 * BKK]);
            async16(Bt + (brow0 + r0 + srow) * K + k0 + scol, &Bs[r0 * BKK]);
        }
        __syncthreads();
        const int lr = lane & 15;
        const int r7 = lane & 7;                   // (row&7) for all fragment rows
#pragma unroll
        for (int kk = 0; kk < BKK; kk += 32) {
            const int c0 = (kk >> 3) + (lane >> 4); // 16B-chunk index pre-swizzle
            short8 a[4], b[4];
#pragma unroll
            for (int m = 0; m < 4; ++m)
                a[m] = *(const short8*)&As[(wr * 64 + m * 16 + lr) * BKK + ((c0 ^ r7) * 8)];
#pragma unroll
            for (int n = 0; n < 4; ++n)
                b[n] = *(const short8*)&Bs[(wc * 64 + n * 16 + lr) * BKK + ((c0 ^ r7) * 8)];
#pragma unroll
            for (int m = 0; m < 4; ++m)
#pragma unroll
                for (int n = 0; n < 4; ++n)
                    acc[m][n] = __builtin_amdgcn_mfma_f32_16x16x32_bf16(
                        a[m], b[n], acc[m][n], 0, 0, 0);
        }
    }

    // ---- epilogue: acc -> (bias, GELU, bf16) -> wave-private LDS -> 16B stores ----
    __syncthreads();                               // all ds_reads of As/Bs done
    short* E = smem + w * (64 * 72);               // [64 rows][72 cols] (144B rows, 16B-aligned)
    const int cl = lane & 15;
    const int rl = (lane >> 4) * 4;
#pragma unroll
    for (int n = 0; n < 4; ++n) {
        const int col = (int)brow0 + wc * 64 + n * 16 + cl;
        const float bs = bias[col];
#pragma unroll
        for (int m = 0; m < 4; ++m) {
#pragma unroll
            for (int i = 0; i < 4; ++i) {
                float cv = acc[m][n][i] + bs;
                if (GELU) cv = gelu_t(cv);
                E[(m * 16 + rl + i) * 72 + n * 16 + cl] = f2b(cv);
            }
        }
    }
    // wave-private region: no barrier needed (lgkmcnt orders within wave)
#pragma unroll
    for (int chunk = 0; chunk < 8; ++chunk) {
        const int rloc = chunk * 8 + (lane >> 3);
        const int c0   = (lane & 7) * 8;
        short8 v = *(const short8*)&E[rloc * 72 + c0];
        *(short8*)&C[(arow0 + wr * 64 + rloc) * 512 + brow0 + wc * 64 + c0] = v;
    }
}

// ---- transpose+convert: dst[n][k] = bf16(src[k][n]), one 512x512 matrix per blockIdx.z ----
__global__ __launch_bounds__(256)
void transpose_conv(const float* __restrict__ src, short* __restrict__ dst) {
    __shared__ float t[32][33];
    const long moff = (long)blockIdx.z * 512 * 512;
    const float* s = src + moff;
    short* d = dst + moff;
    const int tx = threadIdx.x & 31, ty = threadIdx.x >> 5;  // ty 0..7
    const int bi = blockIdx.x, bj = blockIdx.y;
#pragma unroll
    for (int j = 0; j < 4; ++j)
        t[ty + j * 8][tx] = s[(long)(bi * 32 + ty + j * 8) * 512 + bj * 32 + tx];
    __syncthreads();
#pragma unroll
    for (int j = 0; j < 4; ++j)
        d[(long)(bj * 32 + ty + j * 8) * 512 + bi * 32 + tx] = f2b(t[tx][ty + j * 8]);
}

// ---- f32 -> bf16 elementwise ----
__global__ __launch_bounds__(256)
void conv_f32_bf16(const float* __restrict__ src, short* __restrict__ dst, long n) {
    long i = ((long)blockIdx.x * 256 + threadIdx.x) * 4;
    if (i >= n) return;
    float4 f = *(const float4*)&src[i];
    short4v o;
    o[0] = f2b(f.x); o[1] = f2b(f.y); o[2] = f2b(f.z); o[3] = f2b(f.w);
    *(short4v*)&dst[i] = o;
}

// ---- LayerNorm + L2 normalize: one wave per 512-row ----
__global__ __launch_bounds__(256)
void ln_normalize(const short* __restrict__ in, const float* __restrict__ g,
                  const float* __restrict__ bta, short* __restrict__ outz, long nrows) {
    const int wid = threadIdx.x >> 6, lane = threadIdx.x & 63;
    const long row = (long)blockIdx.x * 4 + wid;
    if (row >= nrows) return;
    short8 t = *(const short8*)&in[row * 512 + lane * 8];
    float v[8];
    float s = 0.f, ss = 0.f;
#pragma unroll
    for (int j = 0; j < 8; ++j) { v[j] = b2f(t[j]); s += v[j]; ss += v[j] * v[j]; }
#pragma unroll
    for (int o = 1; o < 64; o <<= 1) { s += __shfl_xor(s, o, 64); ss += __shfl_xor(ss, o, 64); }
    const float mu = s * (1.f / 512.f);
    const float var = ss * (1.f / 512.f) - mu * mu;
    const float rs = rsqrtf(var + 1e-5f);
    float y[8]; float nsq = 0.f;
#pragma unroll
    for (int j = 0; j < 8; ++j) {
        const int col = lane * 8 + j;
        y[j] = (v[j] - mu) * rs * g[col] + bta[col];
        nsq += y[j] * y[j];
    }
#pragma unroll
    for (int o = 1; o < 64; o <<= 1) nsq += __shfl_xor(nsq, o, 64);
    const float inv = 1.f / fmaxf(sqrtf(nsq), 1e-8f);
    short8 o8;
#pragma unroll
    for (int j = 0; j < 8; ++j) o8[j] = f2b(y[j] * inv);
    *(short8*)&outz[row * 512 + lane * 8] = o8;
}

// ---- loss: 4 waves/block, one b per wave; 12x12 Gram + per-k logsumexp ----
__global__ __launch_bounds__(256)
void loss_kernel(const short* __restrict__ Z, float* __restrict__ out, int CH) {
    const int wid = threadIdx.x >> 6, lane = threadIdx.x & 63;
    const long b = (long)blockIdx.x * 4 + wid;
    __shared__ float G[4][12][12];
    float v[12][8];
#pragma unroll
    for (int sIdx = 0; sIdx < 12; ++sIdx) {
        short8 t = *(const short8*)&Z[((long)sIdx * CH + b) * 512 + lane * 8];
#pragma unroll
        for (int j = 0; j < 8; ++j) v[sIdx][j] = b2f(t[j]);
    }
#pragma unroll
    for (int i = 0; i < 12; ++i) {
#pragma unroll
        for (int j = i + 1; j < 12; ++j) {
            float p = 0.f;
#pragma unroll
            for (int t = 0; t < 8; ++t) p += v[i][t] * v[j][t];
#pragma unroll
            for (int o = 1; o < 64; o <<= 1) p += __shfl_xor(p, o, 64);
            if (lane == 0) { G[wid][i][j] = p; G[wid][j][i] = p; }
        }
    }
    __syncthreads();
    float contrib = 0.f;
    if (lane >= 1 && lane <= 11) {
        const int k = lane;
        const float pos = G[wid][0][k];
        float mx = pos;
        for (int l = 1; l <= 11; ++l) if (l != k) mx = fmaxf(mx, G[wid][l][k]);
        float sum = expf(pos - mx);
        for (int l = 1; l <= 11; ++l) if (l != k) sum += expf(G[wid][l][k] - mx);
        contrib = pos - (mx + logf(sum));
    }
#pragma unroll
    for (int o = 1; o < 64; o <<= 1) contrib += __shfl_xor(contrib, o, 64);
    if (lane == 0) out[b] = -contrib;
}

// ---------------- host ----------------
extern "C" void kernel_launch(void* const* d_in, const int* in_sizes, int n_in,
                              void* d_out, int out_size, void* d_ws, size_t ws_size,
                              hipStream_t stream) {
    const float* x    = (const float*)d_in[0];
    const float* tW1  = (const float*)d_in[1];
    const float* tb1  = (const float*)d_in[2];
    const float* tW2  = (const float*)d_in[3];
    const float* tb2  = (const float*)d_in[4];
    const float* tW3  = (const float*)d_in[5];
    const float* tb3  = (const float*)d_in[6];
    const float* eW1  = (const float*)d_in[7];
    const float* eb1  = (const float*)d_in[8];
    const float* eW2  = (const float*)d_in[9];
    const float* eb2  = (const float*)d_in[10];
    const float* eW3  = (const float*)d_in[11];
    const float* eb3  = (const float*)d_in[12];
    const float* ln_g = (const float*)d_in[13];
    const float* ln_b = (const float*)d_in[14];

    const int  B    = in_sizes[0] / 512;   // 16384
    const long WMAT = 512L * 512L;

    // ---- adaptive chunking: footprint = weights + 3 slabs of 12*CH*512 bf16 ----
    int  c  = 1;
    long CH = B;
    for (;;) {
        CH = (long)B / c;
        size_t need = (size_t)36 * WMAT * 2 + (size_t)36 * CH * 512 * 2 + 4096;
        if (need <= ws_size || CH <= 256) break;
        c <<= 1;
    }
    const long SLAB = 12L * CH * 512;      // elements per 12-view slab

    short* wt  = (short*)d_ws;             // 36 transposed bf16 weight mats
    short* X12 = wt  + 36L * WMAT;         // [12, CH, 512]: slot0 = x, 1..11 = t_k(x); reused as z-store
    short* hA  = X12 + SLAB;               // [12, CH, 512] scratch
    short* hB  = hA  + SLAB;               // [12, CH, 512] scratch

    // --- weight transpose+convert (once) ---
    {
        dim3 tgK(16, 16, 11), tg1(16, 16, 1);
        transpose_conv<<<tgK, 256, 0, stream>>>(tW1, wt + 0L * WMAT);
        transpose_conv<<<tgK, 256, 0, stream>>>(tW2, wt + 11L * WMAT);
        transpose_conv<<<tgK, 256, 0, stream>>>(tW3, wt + 22L * WMAT);
        transpose_conv<<<tg1, 256, 0, stream>>>(eW1, wt + 33L * WMAT);
        transpose_conv<<<tg1, 256, 0, stream>>>(eW2, wt + 34L * WMAT);
        transpose_conv<<<tg1, 256, 0, stream>>>(eW3, wt + 35L * WMAT);
    }

    const long SC = CH * 512;              // one [CH,512] slab
    const dim3 gT((unsigned)(CH / BM), 512 / BN, 11);        // batched transforms
    const dim3 gE((unsigned)(12 * CH / BM), 512 / BN, 1);    // encoder over all 12 views
    const dim3 lng((unsigned)((12 * CH) / 4));

    for (int ch = 0; ch < c; ++ch) {
        // x chunk -> bf16 into X12 slot 0
        conv_f32_bf16<<<(unsigned)((SC / 4 + 255) / 256), 256, 0, stream>>>(
            x + (long)ch * SC, X12, SC);

        // 11 learned transforms, batched over z
        gemm_bt<true ><<<gT, 256, 0, stream>>>(X12, 0,  wt + 0L * WMAT,  WMAT, tb1, 512, hA, SC);
        gemm_bt<true ><<<gT, 256, 0, stream>>>(hA,  SC, wt + 11L * WMAT, WMAT, tb2, 512, hB, SC);
        gemm_bt<false><<<gT, 256, 0, stream>>>(hB,  SC, wt + 22L * WMAT, WMAT, tb3, 512, X12 + SC, SC);

        // shared encoder over all 12 views at once (M = 12*CH)
        gemm_bt<true ><<<gE, 256, 0, stream>>>(X12, 0, wt + 33L * WMAT, 0, eb1, 0, hA, 0);
        gemm_bt<true ><<<gE, 256, 0, stream>>>(hA,  0, wt + 34L * WMAT, 0, eb2, 0, hB, 0);
        gemm_bt<false><<<gE, 256, 0, stream>>>(hB,  0, wt + 35L * WMAT, 0, eb3, 0, hA, 0);

        // LN + L2-normalize all 12*CH rows; write z back into X12 (free after E1 read)
        ln_normalize<<<lng, 256, 0, stream>>>(hA, ln_g, ln_b, X12, 12L * CH);

        // per-sample 12x12 Gram + logsumexp loss
        loss_kernel<<<(unsigned)(CH / 4), 256, 0, stream>>>(X12, (float*)d_out + (long)ch * CH, (int)CH);
    }
}